// Round 1
// 561.387 us; speedup vs baseline: 1.2320x; 1.2320x over previous
//
#include <hip/hip_runtime.h>
#include <math.h>

#define TOKENS 4096
#define EMBD   1024
#define HID    4096
#define NE     8
#define SLOTC  8320   // padded slot capacity (8192 used)

typedef __attribute__((ext_vector_type(8))) short short8;
typedef __attribute__((ext_vector_type(4))) float f32x4;

#define GLOBAL_PTR(p) ((const __attribute__((address_space(1))) void*)(p))
#define LDS_PTR(p)    ((__attribute__((address_space(3))) void*)(p))

// LDS fragment address with XOR chunk swizzle (shorts). Chunk q lives at
// granule q ^ ((row>>1)&3) -> 16-lane read phases hit 8 bank-quads x2 = free.
#define SWZ(row, q) ((row) * 32 + (((q) ^ (((row) >> 1) & 3)) * 8))

__device__ __forceinline__ unsigned short f2bf(float f) {
  unsigned int u = __float_as_uint(f);
  u += 0x7FFFu + ((u >> 16) & 1u);   // round-to-nearest-even
  return (unsigned short)(u >> 16);
}
__device__ __forceinline__ float bf2f(unsigned short h) {
  return __uint_as_float((unsigned int)h << 16);
}

// exact-GELU via Abramowitz-Stegun 7.1.26 erf (|eps| < 1.5e-7), ~12 VALU ops
__device__ __forceinline__ float fast_gelu(float v) {
  float u = fabsf(v) * 0.70710678118654752f;
  float t = 1.0f / (1.0f + 0.3275911f * u);
  float poly = ((((1.061405429f * t - 1.453152027f) * t + 1.421413741f) * t
                 - 0.284496736f) * t + 0.254829592f) * t;
  float erf_abs = 1.0f - poly * __expf(-u * u);
  float er = (v < 0.0f) ? -erf_abs : erf_abs;
  return 0.5f * v * (1.0f + er);
}

// ---------- fused gate + x fp32->bf16 convert. One wave per token. ----------
// (atomics removed; counting moved to k_count to kill same-line serialization)
__global__ __launch_bounds__(256) void k_gate_cvt(const float* __restrict__ x,
                                                  const float* __restrict__ gw,
                                                  unsigned short* __restrict__ xb,
                                                  int* __restrict__ idx2,
                                                  float* __restrict__ wv) {
  int wave = threadIdx.x >> 6, lane = threadIdx.x & 63;
  int t = blockIdx.x * 4 + wave;
  const float4* xr = (const float4*)(x + (size_t)t * EMBD);   // 256 float4
  ushort4* xbr = (ushort4*)(xb + (size_t)t * EMBD);
  float acc[NE];
#pragma unroll
  for (int e = 0; e < NE; e++) acc[e] = 0.f;
#pragma unroll
  for (int ch = 0; ch < 4; ch++) {
    int i = ch * 64 + lane;
    float4 v = xr[i];
    ushort4 o;
    o.x = f2bf(v.x); o.y = f2bf(v.y); o.z = f2bf(v.z); o.w = f2bf(v.w);
    xbr[i] = o;
    int c = i * 4;
    const float* g0 = gw + (size_t)c * NE;
#pragma unroll
    for (int e = 0; e < NE; e++) acc[e] += v.x * g0[e];
#pragma unroll
    for (int e = 0; e < NE; e++) acc[e] += v.y * g0[NE + e];
#pragma unroll
    for (int e = 0; e < NE; e++) acc[e] += v.z * g0[2 * NE + e];
#pragma unroll
    for (int e = 0; e < NE; e++) acc[e] += v.w * g0[3 * NE + e];
  }
#pragma unroll
  for (int e = 0; e < NE; e++) {
#pragma unroll
    for (int off = 32; off > 0; off >>= 1) acc[e] += __shfl_down(acc[e], off);
  }
  if (lane == 0) {
    float best = -1e30f, second = -1e30f;
    int bi = 0, si = 0;
#pragma unroll
    for (int e = 0; e < NE; e++) {
      float l = acc[e];
      if (l > best) { second = best; si = bi; best = l; bi = e; }
      else if (l > second) { second = l; si = e; }
    }
    float b = expf(second - best);
    float w0 = 1.f / (1.f + b);
    float w1 = b / (1.f + b);
    idx2[2 * t] = bi; idx2[2 * t + 1] = si;
    wv[2 * t] = w0; wv[2 * t + 1] = w1;
  }
}

// ---------- histogram + prefix in one tiny kernel (replaces zero_ctrl+scan) ----
__global__ __launch_bounds__(256) void k_count(const int* __restrict__ idx2,
                                               int* __restrict__ ctrl) {
  __shared__ int cnt[NE];
  int tid = threadIdx.x;
  if (tid < NE) cnt[tid] = 0;
  __syncthreads();
  for (int i = tid; i < TOKENS * 2; i += 256) atomicAdd(&cnt[idx2[i]], 1);
  __syncthreads();
  if (tid == 0) {
    int off = 0;
#pragma unroll
    for (int e = 0; e < NE; e++) { int c = cnt[e]; ctrl[e] = c; ctrl[8 + e] = off; off += c; }
    ctrl[16] = off;
  }
  if (tid < NE) ctrl[17 + tid] = 0;
}

// ---------- slot assignment: two-level (LDS positions, 8 global atomics/blk) ---
__global__ __launch_bounds__(256) void k_assign(const int* __restrict__ idx2,
                                                int* __restrict__ ctrl,
                                                int* __restrict__ token_list,
                                                int* __restrict__ tok2slot) {
  __shared__ int lpos[NE];
  __shared__ int lbase[NE];
  int tid = threadIdx.x;
  int t = blockIdx.x * 256 + tid;
  if (tid < NE) lpos[tid] = 0;
  __syncthreads();
  int e0 = idx2[2 * t], e1 = idx2[2 * t + 1];
  int p0 = atomicAdd(&lpos[e0], 1);
  int p1 = atomicAdd(&lpos[e1], 1);
  __syncthreads();
  if (tid < NE) lbase[tid] = atomicAdd(&ctrl[17 + tid], lpos[tid]);
  __syncthreads();
  int s0 = ctrl[8 + e0] + lbase[e0] + p0;
  int s1 = ctrl[8 + e1] + lbase[e1] + p1;
  token_list[s0] = t;
  token_list[s1] = t;
  tok2slot[2 * t] = s0;
  tok2slot[2 * t + 1] = s1;
}

// ---------- transpose+convert: in [e][R][C] fp32 -> out [e][C][R] bf16 ----------
__global__ __launch_bounds__(256) void k_trans(const float* __restrict__ in,
                                               unsigned short* __restrict__ out,
                                               int R, int C) {
  __shared__ unsigned short T[64 * 66];   // [col][row], pad 66
  int e = blockIdx.z;
  const float* ine = in + (size_t)e * R * C;
  unsigned short* oute = out + (size_t)e * R * C;
  int r0 = blockIdx.y * 64;
  int c0 = blockIdx.x * 64;
  int tid = threadIdx.x;
  {
    int c4 = tid & 15;          // float4 col chunk
    int rb = tid >> 4;          // 0..15
#pragma unroll
    for (int it = 0; it < 4; it++) {
      int r = rb + 16 * it;
      float4 v = *(const float4*)(ine + (size_t)(r0 + r) * C + c0 + 4 * c4);
      T[(4 * c4 + 0) * 66 + r] = f2bf(v.x);
      T[(4 * c4 + 1) * 66 + r] = f2bf(v.y);
      T[(4 * c4 + 2) * 66 + r] = f2bf(v.z);
      T[(4 * c4 + 3) * 66 + r] = f2bf(v.w);
    }
  }
  __syncthreads();
  {
    int rr = tid & 7;           // 16B chunk along output row
    int cq = tid >> 3;          // 0..31
#pragma unroll
    for (int it = 0; it < 2; it++) {
      int c = cq + 32 * it;     // output row (= input col)
      short8 o;
#pragma unroll
      for (int k = 0; k < 8; k++) o[k] = (short)T[c * 66 + 8 * rr + k];
      *(short8*)(oute + (size_t)(c0 + c) * R + r0 + 8 * rr) = o;
    }
  }
}

// ---------- GEMM1: H = gelu(gather(x) @ w1[e] + b1[e]) ----------
// 1D grid 8192: e = h&7 (XCD-keyed), j = h>>3, n_blk = j&31, m_blk = j>>5.
// Double-buffered LDS; next tile's global_load_lds issued BEFORE current
// tile's compute (T3-minimum 2-phase) to hide LLC/HBM fetch latency.
__global__ __launch_bounds__(256, 2) void k_gemm1(
    const unsigned short* __restrict__ xb,
    const unsigned short* __restrict__ w1t,
    const float* __restrict__ b1,
    const int* __restrict__ ctrl,
    const int* __restrict__ token_list,
    unsigned short* __restrict__ Hbuf) {
  int h = blockIdx.x;
  int e = h & 7;
  int j = h >> 3;
  int nb = (j & 31) * 128;
  int m_base = (j >> 5) * 128;
  int cnt = ctrl[e];
  if (m_base >= cnt) return;
  int off_e = ctrl[8 + e];
  int tid = threadIdx.x;
  int wave = tid >> 6, lane = tid & 63;

  __shared__ __align__(16) unsigned short As[2][128 * 32];
  __shared__ __align__(16) unsigned short Bs[2][128 * 32];

  // staging: lane covers 16B; LDS addr = tid*16 (+4096 for 2nd half).
  // chunk swizzle: lane at stored-chunk (tid&3) fetches global chunk chS.
  int chS = (tid & 3) ^ ((tid >> 3) & 3);
  int rowA0 = tid >> 2;            // rows 0..63
  int rowA1 = 64 + (tid >> 2);     // rows 64..127
  int tok0 = token_list[off_e + min(m_base + rowA0, cnt - 1)];
  int tok1 = token_list[off_e + min(m_base + rowA1, cnt - 1)];
  const unsigned short* srcA0 = xb + (size_t)tok0 * EMBD + chS * 8;
  const unsigned short* srcA1 = xb + (size_t)tok1 * EMBD + chS * 8;
  const unsigned short* wb = w1t + (size_t)e * HID * EMBD;
  const unsigned short* srcB0 = wb + (size_t)(nb + rowA0) * EMBD + chS * 8;
  const unsigned short* srcB1 = wb + (size_t)(nb + rowA1) * EMBD + chS * 8;

  f32x4 acc[4][4];
#pragma unroll
  for (int i = 0; i < 4; i++)
#pragma unroll
    for (int j2 = 0; j2 < 4; j2++) acc[i][j2] = (f32x4){0.f, 0.f, 0.f, 0.f};

  int wm = (wave >> 1) * 64, wn = (wave & 1) * 64;
  int q4 = lane >> 4, cc = lane & 15;

#define STAGE1(buf, k0) do {                                                                            \
    __builtin_amdgcn_global_load_lds(GLOBAL_PTR(srcA0 + (k0)), LDS_PTR((char*)&As[buf][0] + wave * 1024), 16, 0, 0);        \
    __builtin_amdgcn_global_load_lds(GLOBAL_PTR(srcA1 + (k0)), LDS_PTR((char*)&As[buf][0] + 4096 + wave * 1024), 16, 0, 0); \
    __builtin_amdgcn_global_load_lds(GLOBAL_PTR(srcB0 + (k0)), LDS_PTR((char*)&Bs[buf][0] + wave * 1024), 16, 0, 0);        \
    __builtin_amdgcn_global_load_lds(GLOBAL_PTR(srcB1 + (k0)), LDS_PTR((char*)&Bs[buf][0] + 4096 + wave * 1024), 16, 0, 0); \
  } while (0)

#define COMPUTE1(buf) do {                                                                   \
    short8 af[4], bfr[4];                                                                    \
    _Pragma("unroll")                                                                        \
    for (int i = 0; i < 4; i++) af[i] = *(const short8*)(&As[buf][0] + SWZ(wm + i * 16 + cc, q4));   \
    _Pragma("unroll")                                                                        \
    for (int j2 = 0; j2 < 4; j2++) bfr[j2] = *(const short8*)(&Bs[buf][0] + SWZ(wn + j2 * 16 + cc, q4)); \
    _Pragma("unroll")                                                                        \
    for (int i = 0; i < 4; i++)                                                              \
      _Pragma("unroll")                                                                      \
      for (int j2 = 0; j2 < 4; j2++)                                                         \
        acc[i][j2] = __builtin_amdgcn_mfma_f32_16x16x32_bf16(af[i], bfr[j2], acc[i][j2], 0, 0, 0); \
  } while (0)

  STAGE1(0, 0);
  __syncthreads();
  int cur = 0;
  for (int k0 = 32; k0 < EMBD; k0 += 32) {
    STAGE1(cur ^ 1, k0);                       // prefetch next tile
    __builtin_amdgcn_sched_barrier(0);         // keep loads issued before compute
    COMPUTE1(cur);                             // compute current tile
    __syncthreads();                           // drains vmcnt+lgkmcnt: next tile ready
    cur ^= 1;
  }
  COMPUTE1(cur);                               // last tile

  const float* b1e = b1 + (size_t)e * HID;
  float bias[4];
#pragma unroll
  for (int j2 = 0; j2 < 4; j2++) bias[j2] = b1e[nb + wn + j2 * 16 + cc];
#pragma unroll
  for (int i = 0; i < 4; i++) {
#pragma unroll
    for (int r = 0; r < 4; r++) {
      int m_loc = wm + i * 16 + q4 * 4 + r;
      int m = m_base + m_loc;
      if (m < cnt) {
        size_t hrow = (size_t)(off_e + m) * HID;
#pragma unroll
        for (int j2 = 0; j2 < 4; j2++)
          Hbuf[hrow + nb + wn + j2 * 16 + cc] = f2bf(fast_gelu(acc[i][j2][r] + bias[j2]));
      }
    }
  }
#undef STAGE1
#undef COMPUTE1
}

// ---------- GEMM2 (split-K=2): Yp[s][slot] = H[slot] @ w2[e][kslice] ----------
// 1D grid 4096: e = h&7 (XCD-keyed), s = (h>>3)&1, rem = h>>4, m = rem>>3, n = rem&7.
__global__ __launch_bounds__(256, 2) void k_gemm2(
    const unsigned short* __restrict__ Hbuf,
    const unsigned short* __restrict__ w2t,
    const int* __restrict__ ctrl,
    unsigned short* __restrict__ Yp) {
  int h = blockIdx.x;
  int e = h & 7;
  int s = (h >> 3) & 1;
  int rem = h >> 4;
  int m_base = (rem >> 3) * 128;
  int nb = (rem & 7) * 128;
  int cnt = ctrl[e];
  if (m_base >= cnt) return;
  int off_e = ctrl[8 + e];
  int tid = threadIdx.x;
  int wave = tid >> 6, lane = tid & 63;

  __shared__ __align__(16) unsigned short As[2][128 * 32];
  __shared__ __align__(16) unsigned short Bs[2][128 * 32];

  int chS = (tid & 3) ^ ((tid >> 3) & 3);
  int rowA0 = tid >> 2;
  int rowA1 = 64 + (tid >> 2);
  const unsigned short* srcA0 = Hbuf + (size_t)(off_e + m_base + rowA0) * HID + chS * 8;
  const unsigned short* srcA1 = Hbuf + (size_t)(off_e + m_base + rowA1) * HID + chS * 8;
  const unsigned short* wb = w2t + (size_t)e * EMBD * HID;
  const unsigned short* srcB0 = wb + (size_t)(nb + rowA0) * HID + chS * 8;
  const unsigned short* srcB1 = wb + (size_t)(nb + rowA1) * HID + chS * 8;

  f32x4 acc[4][4];
#pragma unroll
  for (int i = 0; i < 4; i++)
#pragma unroll
    for (int j2 = 0; j2 < 4; j2++) acc[i][j2] = (f32x4){0.f, 0.f, 0.f, 0.f};

  int wm = (wave >> 1) * 64, wn = (wave & 1) * 64;
  int q4 = lane >> 4, cc = lane & 15;

#define STAGE2(buf, k0) do {                                                                            \
    __builtin_amdgcn_global_load_lds(GLOBAL_PTR(srcA0 + (k0)), LDS_PTR((char*)&As[buf][0] + wave * 1024), 16, 0, 0);        \
    __builtin_amdgcn_global_load_lds(GLOBAL_PTR(srcA1 + (k0)), LDS_PTR((char*)&As[buf][0] + 4096 + wave * 1024), 16, 0, 0); \
    __builtin_amdgcn_global_load_lds(GLOBAL_PTR(srcB0 + (k0)), LDS_PTR((char*)&Bs[buf][0] + wave * 1024), 16, 0, 0);        \
    __builtin_amdgcn_global_load_lds(GLOBAL_PTR(srcB1 + (k0)), LDS_PTR((char*)&Bs[buf][0] + 4096 + wave * 1024), 16, 0, 0); \
  } while (0)

#define COMPUTE2(buf) do {                                                                   \
    short8 af[4], bfr[4];                                                                    \
    _Pragma("unroll")                                                                        \
    for (int i = 0; i < 4; i++) af[i] = *(const short8*)(&As[buf][0] + SWZ(wm + i * 16 + cc, q4));   \
    _Pragma("unroll")                                                                        \
    for (int j2 = 0; j2 < 4; j2++) bfr[j2] = *(const short8*)(&Bs[buf][0] + SWZ(wn + j2 * 16 + cc, q4)); \
    _Pragma("unroll")                                                                        \
    for (int i = 0; i < 4; i++)                                                              \
      _Pragma("unroll")                                                                      \
      for (int j2 = 0; j2 < 4; j2++)                                                         \
        acc[i][j2] = __builtin_amdgcn_mfma_f32_16x16x32_bf16(af[i], bfr[j2], acc[i][j2], 0, 0, 0); \
  } while (0)

  int kbeg = s * (HID / 2), kend = kbeg + HID / 2;
  STAGE2(0, kbeg);
  __syncthreads();
  int cur = 0;
  for (int k0 = kbeg + 32; k0 < kend; k0 += 32) {
    STAGE2(cur ^ 1, k0);
    __builtin_amdgcn_sched_barrier(0);
    COMPUTE2(cur);
    __syncthreads();
    cur ^= 1;
  }
  COMPUTE2(cur);

  unsigned short* Yps = Yp + (size_t)s * SLOTC * EMBD;
#pragma unroll
  for (int i = 0; i < 4; i++) {
#pragma unroll
    for (int r = 0; r < 4; r++) {
      int m_loc = wm + i * 16 + q4 * 4 + r;
      int m = m_base + m_loc;
      if (m < cnt) {
        size_t yrow = (size_t)(off_e + m) * EMBD;
#pragma unroll
        for (int j2 = 0; j2 < 4; j2++)
          Yps[yrow + nb + wn + j2 * 16 + cc] = f2bf(acc[i][j2][r]);
      }
    }
  }
#undef STAGE2
#undef COMPUTE2
}

// ---------- combine: out[t] = sum_k wv_k * (b2[e_k] + sum_s Yp[s][slot_k]) ----------
__global__ __launch_bounds__(256) void k_combine(const unsigned short* __restrict__ Yp,
                                                 const float* __restrict__ b2,
                                                 const int* __restrict__ idx2,
                                                 const float* __restrict__ wv,
                                                 const int* __restrict__ tok2slot,
                                                 float* __restrict__ out) {
  int t = blockIdx.x;
  int tid = threadIdx.x;
  int c = tid * 4;
  int e0 = idx2[2 * t], e1 = idx2[2 * t + 1];
  float w0 = wv[2 * t], w1 = wv[2 * t + 1];
  int s0 = tok2slot[2 * t], s1 = tok2slot[2 * t + 1];
  ushort4 p00 = *(const ushort4*)(Yp + ((size_t)0 * SLOTC + s0) * EMBD + c);
  ushort4 p01 = *(const ushort4*)(Yp + ((size_t)1 * SLOTC + s0) * EMBD + c);
  ushort4 p10 = *(const ushort4*)(Yp + ((size_t)0 * SLOTC + s1) * EMBD + c);
  ushort4 p11 = *(const ushort4*)(Yp + ((size_t)1 * SLOTC + s1) * EMBD + c);
  float4 b20 = *(const float4*)(b2 + (size_t)e0 * EMBD + c);
  float4 b21 = *(const float4*)(b2 + (size_t)e1 * EMBD + c);
  float4 r;
  r.x = w0 * (bf2f(p00.x) + bf2f(p01.x) + b20.x) + w1 * (bf2f(p10.x) + bf2f(p11.x) + b21.x);
  r.y = w0 * (bf2f(p00.y) + bf2f(p01.y) + b20.y) + w1 * (bf2f(p10.y) + bf2f(p11.y) + b21.y);
  r.z = w0 * (bf2f(p00.z) + bf2f(p01.z) + b20.z) + w1 * (bf2f(p10.z) + bf2f(p11.z) + b21.z);
  r.w = w0 * (bf2f(p00.w) + bf2f(p01.w) + b20.w) + w1 * (bf2f(p10.w) + bf2f(p11.w) + b21.w);
  *(float4*)(out + (size_t)t * EMBD + c) = r;
}

extern "C" void kernel_launch(void* const* d_in, const int* in_sizes, int n_in,
                              void* d_out, int out_size, void* d_ws, size_t ws_size,
                              hipStream_t stream) {
  (void)in_sizes; (void)n_in; (void)out_size; (void)ws_size;
  const float* x      = (const float*)d_in[0];
  const float* gate_w = (const float*)d_in[1];
  const float* w1     = (const float*)d_in[2];
  const float* b1     = (const float*)d_in[3];
  const float* w2     = (const float*)d_in[4];
  const float* b2     = (const float*)d_in[5];
  float* out = (float*)d_out;

  char* ws = (char*)d_ws;
  size_t off = 0;
  auto alloc = [&](size_t bytes) {
    char* p = ws + off;
    off += (bytes + 255) & ~(size_t)255;
    return p;
  };
  unsigned short* xb    = (unsigned short*)alloc((size_t)TOKENS * EMBD * 2);
  unsigned short* w1t   = (unsigned short*)alloc((size_t)NE * HID * EMBD * 2);
  unsigned short* w2t   = (unsigned short*)alloc((size_t)NE * EMBD * HID * 2);
  unsigned short* Hbuf  = (unsigned short*)alloc((size_t)SLOTC * HID * 2);
  unsigned short* Yp    = (unsigned short*)alloc((size_t)2 * SLOTC * EMBD * 2);
  int*   token_list     = (int*)alloc((size_t)SLOTC * 4);
  int*   idx2           = (int*)alloc((size_t)TOKENS * 2 * 4);
  float* wv             = (float*)alloc((size_t)TOKENS * 2 * 4);
  int*   tok2slot       = (int*)alloc((size_t)TOKENS * 2 * 4);
  int*   ctrl           = (int*)alloc(32 * 4);

  k_gate_cvt<<<TOKENS / 4, 256, 0, stream>>>(x, gate_w, xb, idx2, wv);
  k_count<<<1, 256, 0, stream>>>(idx2, ctrl);
  k_assign<<<TOKENS / 256, 256, 0, stream>>>(idx2, ctrl, token_list, tok2slot);
  k_trans<<<dim3(HID / 64, EMBD / 64, NE), 256, 0, stream>>>(w1, w1t, EMBD, HID);
  k_trans<<<dim3(EMBD / 64, HID / 64, NE), 256, 0, stream>>>(w2, w2t, HID, EMBD);
  k_gemm1<<<8192, 256, 0, stream>>>(xb, w1t, b1, ctrl, token_list, Hbuf);
  k_gemm2<<<4096, 256, 0, stream>>>(Hbuf, w2t, ctrl, Yp);
  k_combine<<<TOKENS, 256, 0, stream>>>(Yp, b2, idx2, wv, tok2slot, out);
}